// Round 1
// baseline (453.083 us; speedup 1.0000x reference)
//
#include <hip/hip_runtime.h>

#define CIN   64
#define COUT  64
#define HH    112
#define WW    112
#define NEXP  4
#define COB   8            // output channels per thread (register block)
#define PIX_PER_BLK 256    // one pixel per thread
#define NTILE (HH * WW / PIX_PER_BLK)   // 49

// ---------------------------------------------------------------------------
// Kernel 1: fold per-expert weights with gates into per-sample effective
// weights.  Weff layout: [n][ci][k][co]  (co fastest -> contiguous float4 for
// the co register block, and coalesced writes here).
// ---------------------------------------------------------------------------
__global__ void fold_weights(const float* __restrict__ W,
                             const float* __restrict__ mask,
                             float* __restrict__ Weff, int B) {
    int idx = blockIdx.x * blockDim.x + threadIdx.x;
    int total = B * CIN * 9 * COUT;
    if (idx >= total) return;
    int co = idx % COUT;
    int t  = idx / COUT;
    int k  = t % 9;
    t /= 9;
    int ci = t % CIN;
    int n  = t / CIN;
    float acc = 0.f;
#pragma unroll
    for (int e = 0; e < NEXP; ++e) {
        float g  = mask[n * NEXP + e];
        float wv = W[(((size_t)(e * COUT + co) * CIN + ci) * 9) + k];
        acc = fmaf(g, wv, acc);
    }
    Weff[idx] = acc;
}

// ---------------------------------------------------------------------------
// Kernel 2: direct conv, weights from precomputed Weff (global, wave-uniform
// addresses -> scalar loads).  Each thread: 1 pixel, COB=8 output channels.
// ---------------------------------------------------------------------------
__global__ __launch_bounds__(PIX_PER_BLK, 4)
void conv_gated(const float* __restrict__ x,
                const float* __restrict__ mask,
                const float* __restrict__ bias,   // original b [E][COUT]
                const float* __restrict__ Weff,
                float* __restrict__ out) {
    const int tile = blockIdx.x % NTILE;
    const int cob  = (blockIdx.x / NTILE) % (COUT / COB);
    const int n    = blockIdx.x / (NTILE * (COUT / COB));
    const int p = tile * PIX_PER_BLK + threadIdx.x;
    const int h = p / WW;
    const int w = p % WW;
    const int co0 = cob * COB;

    // bias: Σ_e gate[n,e] * b[e,co]   (all scalar-pipe loads)
    float acc[COB];
#pragma unroll
    for (int j = 0; j < COB; ++j) {
        float a = 0.f;
#pragma unroll
        for (int e = 0; e < NEXP; ++e)
            a = fmaf(mask[n * NEXP + e], bias[e * COUT + co0 + j], a);
        acc[j] = a;
    }

    const float* xb = x + (((size_t)n * CIN) * HH + h) * WW + w;
    const float* wb = Weff + ((size_t)n * CIN) * 9 * COUT + co0;

    const bool rok0 = (h > 0), rok2 = (h < HH - 1);
    const bool cok0 = (w > 0), cok2 = (w < WW - 1);

    for (int ci = 0; ci < CIN; ++ci) {
        const float* xc = xb + (size_t)ci * (HH * WW);
        const float* wc = wb + (size_t)ci * 9 * COUT;
#pragma unroll
        for (int kh = 0; kh < 3; ++kh) {
            const bool rok = (kh == 0) ? rok0 : ((kh == 2) ? rok2 : true);
#pragma unroll
            for (int kw = 0; kw < 3; ++kw) {
                const bool cok = (kw == 0) ? cok0 : ((kw == 2) ? cok2 : true);
                float xv = (rok && cok) ? xc[(kh - 1) * WW + (kw - 1)] : 0.f;
                const float4* wk = (const float4*)(wc + (kh * 3 + kw) * COUT);
                float4 wa = wk[0];
                float4 wb4 = wk[1];
                acc[0] = fmaf(xv, wa.x, acc[0]);
                acc[1] = fmaf(xv, wa.y, acc[1]);
                acc[2] = fmaf(xv, wa.z, acc[2]);
                acc[3] = fmaf(xv, wa.w, acc[3]);
                acc[4] = fmaf(xv, wb4.x, acc[4]);
                acc[5] = fmaf(xv, wb4.y, acc[5]);
                acc[6] = fmaf(xv, wb4.z, acc[6]);
                acc[7] = fmaf(xv, wb4.w, acc[7]);
            }
        }
    }

    float* ob = out + (((size_t)(n * COUT + co0)) * HH + h) * WW + w;
#pragma unroll
    for (int j = 0; j < COB; ++j)
        ob[(size_t)j * (HH * WW)] = acc[j];
}

// ---------------------------------------------------------------------------
// Fallback (no workspace): fold weights into LDS per block, read via float4.
// ---------------------------------------------------------------------------
__global__ __launch_bounds__(PIX_PER_BLK)
void conv_gated_lds(const float* __restrict__ x,
                    const float* __restrict__ mask,
                    const float* __restrict__ bias,
                    const float* __restrict__ W,
                    float* __restrict__ out) {
    __shared__ float sw[CIN * 9 * COB];   // [ci][k][j], j fastest

    const int tile = blockIdx.x % NTILE;
    const int cob  = (blockIdx.x / NTILE) % (COUT / COB);
    const int n    = blockIdx.x / (NTILE * (COUT / COB));
    const int co0 = cob * COB;

    float g[NEXP];
#pragma unroll
    for (int e = 0; e < NEXP; ++e) g[e] = mask[n * NEXP + e];

    for (int m = threadIdx.x; m < CIN * 9 * COB; m += PIX_PER_BLK) {
        int j  = m % COB;
        int k  = (m / COB) % 9;
        int ci = m / (COB * 9);
        float a = 0.f;
#pragma unroll
        for (int e = 0; e < NEXP; ++e)
            a = fmaf(g[e], W[(((size_t)(e * COUT + co0 + j) * CIN + ci) * 9) + k], a);
        sw[(ci * 9 + k) * COB + j] = a;
    }
    __syncthreads();

    const int p = tile * PIX_PER_BLK + threadIdx.x;
    const int h = p / WW;
    const int w = p % WW;

    float acc[COB];
#pragma unroll
    for (int j = 0; j < COB; ++j) {
        float a = 0.f;
#pragma unroll
        for (int e = 0; e < NEXP; ++e)
            a = fmaf(g[e], bias[e * COUT + co0 + j], a);
        acc[j] = a;
    }

    const float* xb = x + (((size_t)n * CIN) * HH + h) * WW + w;
    const bool rok0 = (h > 0), rok2 = (h < HH - 1);
    const bool cok0 = (w > 0), cok2 = (w < WW - 1);

    for (int ci = 0; ci < CIN; ++ci) {
        const float* xc = xb + (size_t)ci * (HH * WW);
        const float* wc = sw + ci * 9 * COB;
#pragma unroll
        for (int kh = 0; kh < 3; ++kh) {
            const bool rok = (kh == 0) ? rok0 : ((kh == 2) ? rok2 : true);
#pragma unroll
            for (int kw = 0; kw < 3; ++kw) {
                const bool cok = (kw == 0) ? cok0 : ((kw == 2) ? cok2 : true);
                float xv = (rok && cok) ? xc[(kh - 1) * WW + (kw - 1)] : 0.f;
                const float4* wk = (const float4*)(wc + (kh * 3 + kw) * COB);
                float4 wa = wk[0];
                float4 wb4 = wk[1];
                acc[0] = fmaf(xv, wa.x, acc[0]);
                acc[1] = fmaf(xv, wa.y, acc[1]);
                acc[2] = fmaf(xv, wa.z, acc[2]);
                acc[3] = fmaf(xv, wa.w, acc[3]);
                acc[4] = fmaf(xv, wb4.x, acc[4]);
                acc[5] = fmaf(xv, wb4.y, acc[5]);
                acc[6] = fmaf(xv, wb4.z, acc[6]);
                acc[7] = fmaf(xv, wb4.w, acc[7]);
            }
        }
    }

    float* ob = out + (((size_t)(n * COUT + co0)) * HH + h) * WW + w;
#pragma unroll
    for (int j = 0; j < COB; ++j)
        ob[(size_t)j * (HH * WW)] = acc[j];
}

extern "C" void kernel_launch(void* const* d_in, const int* in_sizes, int n_in,
                              void* d_out, int out_size, void* d_ws, size_t ws_size,
                              hipStream_t stream) {
    const float* x    = (const float*)d_in[0];
    const float* mask = (const float*)d_in[1];
    const float* W    = (const float*)d_in[2];
    const float* b    = (const float*)d_in[3];
    float* out  = (float*)d_out;
    float* Weff = (float*)d_ws;

    const int B = in_sizes[0] / (CIN * HH * WW);   // 32
    const size_t weff_elems = (size_t)B * CIN * 9 * COUT;
    const int grid = B * (COUT / COB) * NTILE;

    if (ws_size >= weff_elems * sizeof(float)) {
        int foldBlocks = (int)((weff_elems + 255) / 256);
        fold_weights<<<foldBlocks, 256, 0, stream>>>(W, mask, Weff, B);
        conv_gated<<<grid, PIX_PER_BLK, 0, stream>>>(x, mask, b, Weff, out);
    } else {
        conv_gated_lds<<<grid, PIX_PER_BLK, 0, stream>>>(x, mask, b, W, out);
    }
}

// Round 2
// 123.494 us; speedup vs baseline: 3.6689x; 3.6689x over previous
//
#include <hip/hip_runtime.h>
#include <stdint.h>

#define CIN   64
#define COUT  64
#define HH    112
#define WW    112
#define NEXP  4

typedef short bf16x8 __attribute__((ext_vector_type(8)));
typedef float f32x16 __attribute__((ext_vector_type(16)));

__device__ inline uint16_t f2bf(float f) {
    uint32_t u = __builtin_bit_cast(uint32_t, f);
    return (uint16_t)((u + 0x7FFFu + ((u >> 16) & 1u)) >> 16);
}

// ---------------------------------------------------------------------------
// Pass 1: x [B][64][112][112] f32  ->  Xt [B][114][114][64] bf16, zero-padded
// halo (h,w in [-1,112]).  One block per (n, padded-row).
// ---------------------------------------------------------------------------
__global__ __launch_bounds__(256)
void xform_x(const float* __restrict__ x, uint16_t* __restrict__ Xt) {
    __shared__ float lds[CIN][WW + 1];
    const int hp = blockIdx.x % 114;
    const int n  = blockIdx.x / 114;
    const int h  = hp - 1;
    uint16_t* orow = Xt + ((size_t)(n * 114 + hp)) * 114 * 64;

    if (h < 0 || h >= HH) {
        const uint4 z = {0, 0, 0, 0};
        for (int u = threadIdx.x; u < 114 * 8; u += 256)
            *(uint4*)(orow + u * 8) = z;
        return;
    }
    for (int i = threadIdx.x; i < CIN * WW; i += 256) {
        int ci = i / WW, w = i % WW;
        lds[ci][w] = x[((size_t)(n * CIN + ci)) * (HH * WW) + h * WW + w];
    }
    __syncthreads();
    for (int u = threadIdx.x; u < 114 * 8; u += 256) {
        int wp = u >> 3, cg = u & 7;
        int w = wp - 1;
        union { uint16_t s[8]; uint4 v; } pk;
        if (w < 0 || w >= WW) {
            pk.v = (uint4){0, 0, 0, 0};
        } else {
#pragma unroll
            for (int j = 0; j < 8; ++j) pk.s[j] = f2bf(lds[cg * 8 + j][w]);
        }
        *(uint4*)(orow + (size_t)u * 8) = pk.v;
    }
}

// ---------------------------------------------------------------------------
// Pass 2: fold gates into per-sample weights (bf16, layout [n][co][k=576],
// k = (kh*3+kw)*64 + ci) and biases (f32 [n][64]).
// ---------------------------------------------------------------------------
__global__ __launch_bounds__(256)
void fold_wb(const float* __restrict__ W, const float* __restrict__ bias,
             const float* __restrict__ mask,
             uint16_t* __restrict__ Weff, float* __restrict__ Beff, int B) {
    int idx = blockIdx.x * 256 + threadIdx.x;
    if (idx >= B * COUT * 576) return;
    int k  = idx % 576;
    int co = (idx / 576) % COUT;
    int n  = idx / (576 * COUT);
    int khw = k >> 6, ci = k & 63;
    float acc = 0.f;
#pragma unroll
    for (int e = 0; e < NEXP; ++e)
        acc = fmaf(mask[n * NEXP + e],
                   W[((size_t)(e * COUT + co) * CIN + ci) * 9 + khw], acc);
    Weff[idx] = f2bf(acc);
    if (k == 0) {
        float ba = 0.f;
#pragma unroll
        for (int e = 0; e < NEXP; ++e)
            ba = fmaf(mask[n * NEXP + e], bias[e * COUT + co], ba);
        Beff[n * COUT + co] = ba;
    }
}

// ---------------------------------------------------------------------------
// Pass 3: implicit-GEMM conv via v_mfma_f32_32x32x16_bf16.
// Block = 256 thr (4 waves), one 16x16 pixel tile of one sample, all 64 cout.
// Wave w owns pixel rows 4w..4w+3 (N=64 as 2 n-frags), M=64 as 2 m-frags.
// LDS: X halo tile [18x18(+pad)][64ci] bf16, XOR-swizzled in 16B units.
// ---------------------------------------------------------------------------
__global__ __launch_bounds__(256, 3)
void conv_mfma(const uint16_t* __restrict__ Xt, const uint16_t* __restrict__ Weff,
               const float* __restrict__ Beff, float* __restrict__ out) {
    __shared__ uint16_t ldsx[328 * 64];   // 41984 B

    const int tid  = threadIdx.x;
    const int lane = tid & 63;
    const int wid  = tid >> 6;
    const int tileIdx = blockIdx.x % 49;
    const int n  = blockIdx.x / 49;
    const int th = tileIdx / 7, tw = tileIdx % 7;
    const int h0 = th * 16, w0 = tw * 16;

    // ---- stage X halo tile (pix = dh*18+dw over 18x18), swizzled content:
    // LDS slot (pix, s) holds ci-group s ^ (pix&7)  [T2/G4 swizzle]
    const uint16_t* xbase = Xt + (((size_t)n * 114 + h0) * 114 + w0) * 64;
    for (int u = tid; u < 328 * 8; u += 256) {
        int pix = u >> 3, s = u & 7;
        int p = pix > 323 ? 323 : pix;            // tail units: safe garbage
        int cg = s ^ (p & 7);
        int dh = p / 18, dw = p % 18;
        uint4 v = *(const uint4*)(xbase + ((size_t)dh * 114 + dw) * 64 + cg * 8);
        *(uint4*)(&ldsx[pix * 64 + s * 8]) = v;
    }
    __syncthreads();

    // A-fragment base: lane&31 = co within m-frag, lane>>5 selects k-octet
    const uint16_t* wrow = Weff + (size_t)n * (COUT * 576)
                         + (size_t)(lane & 31) * 576 + ((lane >> 5) << 3);

    const int rowb = wid * 4 + ((lane & 31) >> 4); // pixel row (nf=0)
    const int colb = lane & 15;                    // pixel col
    const int cg0  = (lane >> 5);

    f32x16 acc00 = {}, acc01 = {}, acc10 = {}, acc11 = {};

#pragma unroll 1
    for (int khw = 0; khw < 9; ++khw) {
        const int dh = khw / 3;
        const int dw = khw - dh * 3;
        const int pb0 = (rowb + dh) * 18 + (colb + dw);
        const int pb1 = pb0 + 36;                  // nf=1: +2 pixel rows
        const int x0 = pb0 & 7, x1 = pb1 & 7;
        const uint16_t* lp0 = &ldsx[pb0 * 64];
        const uint16_t* lp1 = &ldsx[pb1 * 64];
#pragma unroll
        for (int kq = 0; kq < 4; ++kq) {
            const int cgA = cg0 + kq * 2;
            bf16x8 b0 = *(const bf16x8*)(lp0 + (((cgA ^ x0)) << 3));
            bf16x8 b1 = *(const bf16x8*)(lp1 + (((cgA ^ x1)) << 3));
            bf16x8 a0 = *(const bf16x8*)(wrow + kq * 16);
            bf16x8 a1 = *(const bf16x8*)(wrow + 32 * 576 + kq * 16);
            acc00 = __builtin_amdgcn_mfma_f32_32x32x16_bf16(a0, b0, acc00, 0, 0, 0);
            acc01 = __builtin_amdgcn_mfma_f32_32x32x16_bf16(a0, b1, acc01, 0, 0, 0);
            acc10 = __builtin_amdgcn_mfma_f32_32x32x16_bf16(a1, b0, acc10, 0, 0, 0);
            acc11 = __builtin_amdgcn_mfma_f32_32x32x16_bf16(a1, b1, acc11, 0, 0, 0);
        }
        wrow += 64;   // next khw block (4 K-steps * 16 elems)
    }

    // ---- epilogue: C/D layout col=lane&31 (pixel), row=(r&3)+8*(r>>2)+4*(lane>>5)
    const float* bptr = Beff + n * 64;
    const int row0 = h0 + wid * 4 + ((lane & 31) >> 4);
    const int col  = w0 + (lane & 15);
#pragma unroll
    for (int r = 0; r < 16; ++r) {
        const int co = (r & 3) + 8 * (r >> 2) + 4 * (lane >> 5);
        const float bia0 = bptr[co];
        const float bia1 = bptr[co + 32];
        size_t o00 = ((size_t)(n * COUT + co) * HH + row0) * WW + col;
        out[o00]            = acc00[r] + bia0;
        out[o00 + 2 * WW]   = acc01[r] + bia0;
        size_t o10 = o00 + (size_t)32 * HH * WW;
        out[o10]            = acc10[r] + bia1;
        out[o10 + 2 * WW]   = acc11[r] + bia1;
    }
}

// ---------------------------------------------------------------------------
// Fallback (round-1 path): per-sample folded weights, fp32 vector conv.
// ---------------------------------------------------------------------------
#define COB   8
#define PIX_PER_BLK 256
#define NTILE (HH * WW / PIX_PER_BLK)

__global__ void fold_weights(const float* __restrict__ W,
                             const float* __restrict__ mask,
                             float* __restrict__ Weff, int B) {
    int idx = blockIdx.x * blockDim.x + threadIdx.x;
    int total = B * CIN * 9 * COUT;
    if (idx >= total) return;
    int co = idx % COUT;
    int t  = idx / COUT;
    int k  = t % 9;
    t /= 9;
    int ci = t % CIN;
    int n  = t / CIN;
    float acc = 0.f;
#pragma unroll
    for (int e = 0; e < NEXP; ++e)
        acc = fmaf(mask[n * NEXP + e],
                   W[(((size_t)(e * COUT + co) * CIN + ci) * 9) + k], acc);
    Weff[idx] = acc;
}

__global__ __launch_bounds__(PIX_PER_BLK, 4)
void conv_gated(const float* __restrict__ x,
                const float* __restrict__ mask,
                const float* __restrict__ bias,
                const float* __restrict__ Weff,
                float* __restrict__ out) {
    const int tile = blockIdx.x % NTILE;
    const int cob  = (blockIdx.x / NTILE) % (COUT / COB);
    const int n    = blockIdx.x / (NTILE * (COUT / COB));
    const int p = tile * PIX_PER_BLK + threadIdx.x;
    const int h = p / WW;
    const int w = p % WW;
    const int co0 = cob * COB;

    float acc[COB];
#pragma unroll
    for (int j = 0; j < COB; ++j) {
        float a = 0.f;
#pragma unroll
        for (int e = 0; e < NEXP; ++e)
            a = fmaf(mask[n * NEXP + e], bias[e * COUT + co0 + j], a);
        acc[j] = a;
    }

    const float* xb = x + (((size_t)n * CIN) * HH + h) * WW + w;
    const float* wb = Weff + ((size_t)n * CIN) * 9 * COUT + co0;
    const bool rok0 = (h > 0), rok2 = (h < HH - 1);
    const bool cok0 = (w > 0), cok2 = (w < WW - 1);

    for (int ci = 0; ci < CIN; ++ci) {
        const float* xc = xb + (size_t)ci * (HH * WW);
        const float* wc = wb + (size_t)ci * 9 * COUT;
#pragma unroll
        for (int kh = 0; kh < 3; ++kh) {
            const bool rok = (kh == 0) ? rok0 : ((kh == 2) ? rok2 : true);
#pragma unroll
            for (int kw = 0; kw < 3; ++kw) {
                const bool cok = (kw == 0) ? cok0 : ((kw == 2) ? cok2 : true);
                float xv = (rok && cok) ? xc[(kh - 1) * WW + (kw - 1)] : 0.f;
                const float4* wk = (const float4*)(wc + (kh * 3 + kw) * COUT);
                float4 wa = wk[0], wb4 = wk[1];
                acc[0] = fmaf(xv, wa.x, acc[0]);
                acc[1] = fmaf(xv, wa.y, acc[1]);
                acc[2] = fmaf(xv, wa.z, acc[2]);
                acc[3] = fmaf(xv, wa.w, acc[3]);
                acc[4] = fmaf(xv, wb4.x, acc[4]);
                acc[5] = fmaf(xv, wb4.y, acc[5]);
                acc[6] = fmaf(xv, wb4.z, acc[6]);
                acc[7] = fmaf(xv, wb4.w, acc[7]);
            }
        }
    }
    float* ob = out + (((size_t)(n * COUT + co0)) * HH + h) * WW + w;
#pragma unroll
    for (int j = 0; j < COB; ++j)
        ob[(size_t)j * (HH * WW)] = acc[j];
}

// ---------------------------------------------------------------------------
extern "C" void kernel_launch(void* const* d_in, const int* in_sizes, int n_in,
                              void* d_out, int out_size, void* d_ws, size_t ws_size,
                              hipStream_t stream) {
    const float* x    = (const float*)d_in[0];
    const float* mask = (const float*)d_in[1];
    const float* W    = (const float*)d_in[2];
    const float* b    = (const float*)d_in[3];
    float* out = (float*)d_out;

    const int B = in_sizes[0] / (CIN * HH * WW);
    const size_t weffB = (size_t)B * COUT * 576 * 2;
    const size_t beffB = (size_t)B * COUT * 4;
    const size_t xtB   = (size_t)B * 114 * 114 * 64 * 2;
    const size_t need  = weffB + beffB + xtB;

    if (ws_size >= need) {
        uint16_t* Weff = (uint16_t*)d_ws;
        float*    Beff = (float*)((char*)d_ws + weffB);
        uint16_t* Xt   = (uint16_t*)((char*)d_ws + weffB + beffB);
        int foldBlocks = (B * COUT * 576 + 255) / 256;
        fold_wb<<<foldBlocks, 256, 0, stream>>>(W, b, mask, Weff, Beff, B);
        xform_x<<<B * 114, 256, 0, stream>>>(x, Xt);
        conv_mfma<<<B * 49, 256, 0, stream>>>(Xt, Weff, Beff, out);
    } else {
        float* Weff = (float*)d_ws;
        const size_t weff_elems = (size_t)B * CIN * 9 * COUT;
        int foldBlocks = (int)((weff_elems + 255) / 256);
        fold_weights<<<foldBlocks, 256, 0, stream>>>(W, mask, Weff, B);
        conv_gated<<<B * (COUT / COB) * NTILE, PIX_PER_BLK, 0, stream>>>(
            x, mask, b, Weff, out);
    }
}

// Round 3
// 96.583 us; speedup vs baseline: 4.6911x; 1.2786x over previous
//
#include <hip/hip_runtime.h>
#include <stdint.h>

#define CIN   64
#define COUT  64
#define HH    112
#define WW    112
#define NEXP  4

typedef short bf16x8 __attribute__((ext_vector_type(8)));
typedef float f32x16 __attribute__((ext_vector_type(16)));

__device__ inline uint16_t f2bf(float f) {
    uint32_t u = __builtin_bit_cast(uint32_t, f);
    return (uint16_t)((u + 0x7FFFu + ((u >> 16) & 1u)) >> 16);
}

// ---------------------------------------------------------------------------
// Pass 1: x [B][64][112][112] f32  ->  Xt [B][114][114][64] bf16, zero-padded
// halo (h,w in [-1,112]).  One block per (n, padded-row).
// ---------------------------------------------------------------------------
__global__ __launch_bounds__(256)
void xform_x(const float* __restrict__ x, uint16_t* __restrict__ Xt) {
    __shared__ float lds[CIN][WW + 1];
    const int hp = blockIdx.x % 114;
    const int n  = blockIdx.x / 114;
    const int h  = hp - 1;
    uint16_t* orow = Xt + ((size_t)(n * 114 + hp)) * 114 * 64;

    if (h < 0 || h >= HH) {
        const uint4 z = {0, 0, 0, 0};
        for (int u = threadIdx.x; u < 114 * 8; u += 256)
            *(uint4*)(orow + u * 8) = z;
        return;
    }
    for (int i = threadIdx.x; i < CIN * WW; i += 256) {
        int ci = i / WW, w = i % WW;
        lds[ci][w] = x[((size_t)(n * CIN + ci)) * (HH * WW) + h * WW + w];
    }
    __syncthreads();
    for (int u = threadIdx.x; u < 114 * 8; u += 256) {
        int wp = u >> 3, cg = u & 7;
        int w = wp - 1;
        union { uint16_t s[8]; uint4 v; } pk;
        if (w < 0 || w >= WW) {
            pk.v = (uint4){0, 0, 0, 0};
        } else {
#pragma unroll
            for (int j = 0; j < 8; ++j) pk.s[j] = f2bf(lds[cg * 8 + j][w]);
        }
        *(uint4*)(orow + (size_t)u * 8) = pk.v;
    }
}

// ---------------------------------------------------------------------------
// Pass 2: fold gates into per-sample weights (bf16) and biases (f32).
// NEW Weff layout: [n][oct=72][co=64][j=8], where k = oct*8 + j,
// khw = oct/8, ci = (oct%8)*8 + j.  co is the second-fastest axis so the
// MFMA A-fragment load (lane&31 = co, 16B/lane) is fully coalesced:
// lanes 0-31 read 512 contiguous bytes, lanes 32-63 the adjacent octet.
// ---------------------------------------------------------------------------
__global__ __launch_bounds__(256)
void fold_wb(const float* __restrict__ W, const float* __restrict__ bias,
             const float* __restrict__ mask,
             uint16_t* __restrict__ Weff, float* __restrict__ Beff, int B) {
    int idx = blockIdx.x * 256 + threadIdx.x;
    if (idx >= B * COUT * 576) return;
    int j   = idx & 7;
    int co  = (idx >> 3) & 63;
    int oct = (idx >> 9) % 72;
    int n   = idx / (512 * 72);
    int khw = oct >> 3;
    int ci  = ((oct & 7) << 3) + j;
    float acc = 0.f;
#pragma unroll
    for (int e = 0; e < NEXP; ++e)
        acc = fmaf(mask[n * NEXP + e],
                   W[((size_t)(e * COUT + co) * CIN + ci) * 9 + khw], acc);
    Weff[idx] = f2bf(acc);
    if (oct == 0 && j == 0) {
        float ba = 0.f;
#pragma unroll
        for (int e = 0; e < NEXP; ++e)
            ba = fmaf(mask[n * NEXP + e], bias[e * COUT + co], ba);
        Beff[n * COUT + co] = ba;
    }
}

// ---------------------------------------------------------------------------
// Pass 3: implicit-GEMM conv via v_mfma_f32_32x32x16_bf16.
// Block = 256 thr (4 waves), one 16x16 pixel tile of one sample, all 64 cout.
// LDS: X halo tile [18x18(+pad)][64ci] bf16, XOR-swizzled in 16B units.
// A (weights) read from global with the coalesced oct-major layout.
// ---------------------------------------------------------------------------
__global__ __launch_bounds__(256, 3)
void conv_mfma(const uint16_t* __restrict__ Xt, const uint16_t* __restrict__ Weff,
               const float* __restrict__ Beff, float* __restrict__ out) {
    __shared__ uint16_t ldsx[328 * 64];   // 41984 B

    const int tid  = threadIdx.x;
    const int lane = tid & 63;
    const int wid  = tid >> 6;
    const int tileIdx = blockIdx.x % 49;
    const int n  = blockIdx.x / 49;
    const int th = tileIdx / 7, tw = tileIdx % 7;
    const int h0 = th * 16, w0 = tw * 16;

    // ---- stage X halo tile, swizzled in 16B units: slot s holds cg = s^(pix&7)
    const uint16_t* xbase = Xt + (((size_t)n * 114 + h0) * 114 + w0) * 64;
    for (int u = tid; u < 328 * 8; u += 256) {
        int pix = u >> 3, s = u & 7;
        int p = pix > 323 ? 323 : pix;
        int cg = s ^ (p & 7);
        int dh = p / 18, dw = p % 18;
        uint4 v = *(const uint4*)(xbase + ((size_t)dh * 114 + dw) * 64 + cg * 8);
        *(uint4*)(&ldsx[pix * 64 + s * 8]) = v;
    }
    __syncthreads();

    // A base: per-lane co = lane&31 (16B contiguous across lanes), octet
    // parity = lane>>5; kq/khw advance by whole octets (wave-uniform).
    const uint16_t* wbase = Weff + (size_t)n * (72 * 64 * 8)
                          + ((size_t)(lane >> 5) * 64 + (lane & 31)) * 8;

    const int rowb = wid * 4 + ((lane & 31) >> 4); // pixel row (nf=0)
    const int colb = lane & 15;                    // pixel col

    f32x16 acc00 = {}, acc01 = {}, acc10 = {}, acc11 = {};

#pragma unroll 1
    for (int khw = 0; khw < 9; ++khw) {
        const int dh = khw / 3;
        const int dw = khw - dh * 3;
        const int pb0 = (rowb + dh) * 18 + (colb + dw);
        const int pb1 = pb0 + 36;                  // nf=1: +2 pixel rows
        const int x0 = pb0 & 7, x1 = pb1 & 7;
        const uint16_t* lp0 = &ldsx[pb0 * 64];
        const uint16_t* lp1 = &ldsx[pb1 * 64];
        const int cg0 = (lane >> 5);
        const uint16_t* wk = wbase + (size_t)(khw * 8) * 64 * 8;
#pragma unroll
        for (int kq = 0; kq < 4; ++kq) {
            const int cgA = cg0 + kq * 2;
            bf16x8 b0 = *(const bf16x8*)(lp0 + (((cgA ^ x0)) << 3));
            bf16x8 b1 = *(const bf16x8*)(lp1 + (((cgA ^ x1)) << 3));
            bf16x8 a0 = *(const bf16x8*)(wk + (size_t)(kq * 2) * 64 * 8);
            bf16x8 a1 = *(const bf16x8*)(wk + (size_t)(kq * 2) * 64 * 8 + 32 * 8);
            acc00 = __builtin_amdgcn_mfma_f32_32x32x16_bf16(a0, b0, acc00, 0, 0, 0);
            acc01 = __builtin_amdgcn_mfma_f32_32x32x16_bf16(a0, b1, acc01, 0, 0, 0);
            acc10 = __builtin_amdgcn_mfma_f32_32x32x16_bf16(a1, b0, acc10, 0, 0, 0);
            acc11 = __builtin_amdgcn_mfma_f32_32x32x16_bf16(a1, b1, acc11, 0, 0, 0);
        }
    }

    // ---- epilogue: C/D layout col=lane&31 (pixel), row=(r&3)+8*(r>>2)+4*(lane>>5)
    const float* bptr = Beff + n * 64;
    const int row0 = h0 + wid * 4 + ((lane & 31) >> 4);
    const int col  = w0 + (lane & 15);
#pragma unroll
    for (int r = 0; r < 16; ++r) {
        const int co = (r & 3) + 8 * (r >> 2) + 4 * (lane >> 5);
        const float bia0 = bptr[co];
        const float bia1 = bptr[co + 32];
        size_t o00 = ((size_t)(n * COUT + co) * HH + row0) * WW + col;
        out[o00]            = acc00[r] + bia0;
        out[o00 + 2 * WW]   = acc01[r] + bia0;
        size_t o10 = o00 + (size_t)32 * HH * WW;
        out[o10]            = acc10[r] + bia1;
        out[o10 + 2 * WW]   = acc11[r] + bia1;
    }
}

// ---------------------------------------------------------------------------
// Fallback (round-1 path): per-sample folded weights, fp32 vector conv.
// ---------------------------------------------------------------------------
#define COB   8
#define PIX_PER_BLK 256
#define NTILE (HH * WW / PIX_PER_BLK)

__global__ void fold_weights(const float* __restrict__ W,
                             const float* __restrict__ mask,
                             float* __restrict__ Weff, int B) {
    int idx = blockIdx.x * blockDim.x + threadIdx.x;
    int total = B * CIN * 9 * COUT;
    if (idx >= total) return;
    int co = idx % COUT;
    int t  = idx / COUT;
    int k  = t % 9;
    t /= 9;
    int ci = t % CIN;
    int n  = t / CIN;
    float acc = 0.f;
#pragma unroll
    for (int e = 0; e < NEXP; ++e)
        acc = fmaf(mask[n * NEXP + e],
                   W[(((size_t)(e * COUT + co) * CIN + ci) * 9) + k], acc);
    Weff[idx] = acc;
}

__global__ __launch_bounds__(PIX_PER_BLK, 4)
void conv_gated(const float* __restrict__ x,
                const float* __restrict__ mask,
                const float* __restrict__ bias,
                const float* __restrict__ Weff,
                float* __restrict__ out) {
    const int tile = blockIdx.x % NTILE;
    const int cob  = (blockIdx.x / NTILE) % (COUT / COB);
    const int n    = blockIdx.x / (NTILE * (COUT / COB));
    const int p = tile * PIX_PER_BLK + threadIdx.x;
    const int h = p / WW;
    const int w = p % WW;
    const int co0 = cob * COB;

    float acc[COB];
#pragma unroll
    for (int j = 0; j < COB; ++j) {
        float a = 0.f;
#pragma unroll
        for (int e = 0; e < NEXP; ++e)
            a = fmaf(mask[n * NEXP + e], bias[e * COUT + co0 + j], a);
        acc[j] = a;
    }

    const float* xb = x + (((size_t)n * CIN) * HH + h) * WW + w;
    const float* wb = Weff + ((size_t)n * CIN) * 9 * COUT + co0;
    const bool rok0 = (h > 0), rok2 = (h < HH - 1);
    const bool cok0 = (w > 0), cok2 = (w < WW - 1);

    for (int ci = 0; ci < CIN; ++ci) {
        const float* xc = xb + (size_t)ci * (HH * WW);
        const float* wc = wb + (size_t)ci * 9 * COUT;
#pragma unroll
        for (int kh = 0; kh < 3; ++kh) {
            const bool rok = (kh == 0) ? rok0 : ((kh == 2) ? rok2 : true);
#pragma unroll
            for (int kw = 0; kw < 3; ++kw) {
                const bool cok = (kw == 0) ? cok0 : ((kw == 2) ? cok2 : true);
                float xv = (rok && cok) ? xc[(kh - 1) * WW + (kw - 1)] : 0.f;
                const float4* wk = (const float4*)(wc + (kh * 3 + kw) * COUT);
                float4 wa = wk[0], wb4 = wk[1];
                acc[0] = fmaf(xv, wa.x, acc[0]);
                acc[1] = fmaf(xv, wa.y, acc[1]);
                acc[2] = fmaf(xv, wa.z, acc[2]);
                acc[3] = fmaf(xv, wa.w, acc[3]);
                acc[4] = fmaf(xv, wb4.x, acc[4]);
                acc[5] = fmaf(xv, wb4.y, acc[5]);
                acc[6] = fmaf(xv, wb4.z, acc[6]);
                acc[7] = fmaf(xv, wb4.w, acc[7]);
            }
        }
    }
    float* ob = out + (((size_t)(n * COUT + co0)) * HH + h) * WW + w;
#pragma unroll
    for (int j = 0; j < COB; ++j)
        ob[(size_t)j * (HH * WW)] = acc[j];
}

// ---------------------------------------------------------------------------
extern "C" void kernel_launch(void* const* d_in, const int* in_sizes, int n_in,
                              void* d_out, int out_size, void* d_ws, size_t ws_size,
                              hipStream_t stream) {
    const float* x    = (const float*)d_in[0];
    const float* mask = (const float*)d_in[1];
    const float* W    = (const float*)d_in[2];
    const float* b    = (const float*)d_in[3];
    float* out = (float*)d_out;

    const int B = in_sizes[0] / (CIN * HH * WW);
    const size_t weffB = (size_t)B * COUT * 576 * 2;
    const size_t beffB = (size_t)B * COUT * 4;
    const size_t xtB   = (size_t)B * 114 * 114 * 64 * 2;
    const size_t need  = weffB + beffB + xtB;

    if (ws_size >= need) {
        uint16_t* Weff = (uint16_t*)d_ws;
        float*    Beff = (float*)((char*)d_ws + weffB);
        uint16_t* Xt   = (uint16_t*)((char*)d_ws + weffB + beffB);
        int foldBlocks = (B * COUT * 576 + 255) / 256;
        fold_wb<<<foldBlocks, 256, 0, stream>>>(W, b, mask, Weff, Beff, B);
        xform_x<<<B * 114, 256, 0, stream>>>(x, Xt);
        conv_mfma<<<B * 49, 256, 0, stream>>>(Xt, Weff, Beff, out);
    } else {
        float* Weff = (float*)d_ws;
        const size_t weff_elems = (size_t)B * CIN * 9 * COUT;
        int foldBlocks = (int)((weff_elems + 255) / 256);
        fold_weights<<<foldBlocks, 256, 0, stream>>>(W, mask, Weff, B);
        conv_gated<<<B * (COUT / COB) * NTILE, PIX_PER_BLK, 0, stream>>>(
            x, mask, b, Weff, out);
    }
}